// Round 10
// baseline (116.374 us; speedup 1.0000x reference)
//
#include <hip/hip_runtime.h>

#define BATCH 16384
#define LATENT 128
#define HIDDEN 64
#define INDIM 100
#define KPAD 128
#define TANH_SCALE 2.885390081777927f   // 2*log2(e): exp(2x) = exp2(SCALE*x)

typedef short shortx8 __attribute__((ext_vector_type(8)));
typedef float floatx4 __attribute__((ext_vector_type(4)));

__device__ __forceinline__ unsigned bfbits(float f) {
    union { float f; unsigned u; } v; v.f = f;
    return (v.u + 0x7FFF + ((v.u >> 16) & 1)) >> 16;   // RNE, inputs finite
}

#if __has_builtin(__builtin_amdgcn_exp2f)
#define EXP2F(x) __builtin_amdgcn_exp2f(x)
#else
#define EXP2F(x) __exp2f(x)
#endif
#if __has_builtin(__builtin_amdgcn_rcpf)
#define RCPF(x) __builtin_amdgcn_rcpf(x)
#else
#define RCPF(x) (1.0f / (x))
#endif

#define N_U_BLK (BATCH / 16)                 // 1024 16-row tiles of u
#define N_W_BLK (LATENT * HIDDEN / 16)       // 512  16-row tiles of W1

// ---------------------------------------------------------------------------
// prep (R7, proven): 16-row LDS-transpose tiles, one per 256-thr block.
// ---------------------------------------------------------------------------
__global__ __launch_bounds__(256) void prep_all(const float* __restrict__ u,
                                                const float* __restrict__ W1,
                                                const float* __restrict__ b1,
                                                const float* __restrict__ W2,
                                                const float* __restrict__ b2,
                                                shortx8* __restrict__ uf,
                                                shortx8* __restrict__ wf,
                                                float* __restrict__ b2eff) {
    int bx = blockIdx.x;
    int tid = threadIdx.x;

    if (bx >= N_U_BLK + N_W_BLK) {           // b2eff block
        if (tid < LATENT) {
            float s = b2[tid];
            const float* wp = W2 + tid * HIDDEN;
#pragma unroll 8
            for (int h = 0; h < HIDDEN; h++) s += wp[h];
            b2eff[tid] = s;
        }
        return;
    }

    bool isW = (bx >= N_U_BLK);
    int tileIdx = isW ? (bx - N_U_BLK) : bx;
    int r0 = tileIdx * 16;
    const float* src = isW ? W1 : u;
    float scale = isW ? TANH_SCALE : 1.0f;

    __shared__ short lds[16 * 136];

#pragma unroll
    for (int it = 0; it < 4; it++) {
        int p = it * 256 + tid;
        int rl = p >> 6;
        int kp = (p & 63) * 2;
        float f0 = 0.0f, f1 = 0.0f;
        if (kp < INDIM) {
            const float2 t = *(const float2*)(src + (r0 + rl) * INDIM + kp);
            f0 = t.x * scale; f1 = t.y * scale;
        } else if (kp == INDIM) {
            f0 = isW ? b1[r0 + rl] * TANH_SCALE : 1.0f;
        }
        *(unsigned*)(&lds[rl * 136 + kp]) = bfbits(f0) | (bfbits(f1) << 16);
    }
    __syncthreads();

    {
        int lane = tid & 63;
        int kt = tid >> 6;
        int rl = lane & 15;
        int kb = kt * 32 + ((lane >> 4) << 3);
        shortx8 v = *(const shortx8*)(&lds[rl * 136 + kb]);
        shortx8* dst = isW ? wf : uf;
        dst[((size_t)tileIdx * 4 + kt) * 64 + lane] = v;
    }
}

// ---------------------------------------------------------------------------
// R10 main kernel: LDS-SHARED WEIGHTS + paired groups + rcp-4 epilogue.
// R6-R9 all sat at ~50us: occupancy ~2 waves/SIMD (afr = 64 always-resident
// VGPRs per wave, x4 duplicated per block) left the matrix and VALU pipes
// serialized. Now the latent's 16KB weight tile is staged ONCE into LDS and
// fragments are re-read per MFMA (ds_read_b128, 2-way bank alias = free);
// each chunk read feeds TWO groups' MFMAs (pair loop) so LDS pipe stays
// under the trans-pipe floor. Registers drop ~64/wave -> 4+ waves/SIMD ->
// cross-wave MFMA/VALU overlap (m114) finally happens.
// Epilogue: one v_rcp per nt-quad: ip=rcp(d0*d1*d2*d3), 1/d0=(ip*p23)*d1 etc.
// (trans ops/group: 24 -> 20; product <= ~1e12, no overflow).
// ---------------------------------------------------------------------------
__global__ __launch_bounds__(256, 3) void branch_mlp(const shortx8* __restrict__ uf,
                                                     const shortx8* __restrict__ wf,
                                                     const float* __restrict__ W2,
                                                     const float* __restrict__ b2eff,
                                                     float* __restrict__ out) {
    __shared__ shortx8 wlds[16 * 64];        // 16 chunks x 64 lanes = 16 KB
    int tid = threadIdx.x;
    int lane = tid & 63;
    int w = tid >> 6;
    int bx = blockIdx.x;
    int lat = bx >> 5;
    int G0 = (bx & 31) * 32 + w * 8;
    int q = lane >> 4;

    // stage this latent's weight fragments into LDS (coalesced, once)
    {
        const shortx8* wfl = wf + (size_t)lat * 16 * 64;
#pragma unroll
        for (int j = 0; j < 4; j++) {
            int i = j * 256 + tid;
            wlds[i] = wfl[i];
        }
    }

    // -2*W2 for this lane's 16 h-values (h = nt*16 + q*4 + r)
    float4 w2v[4];
#pragma unroll
    for (int nt = 0; nt < 4; nt++) {
        float4 t = *(const float4*)(W2 + lat * HIDDEN + nt * 16 + q * 4);
        w2v[nt] = make_float4(-2.0f * t.x, -2.0f * t.y, -2.0f * t.z, -2.0f * t.w);
    }
    float b2v = b2eff[lat];

    __syncthreads();

    const shortx8* ua = uf + (size_t)G0 * 4 * 64 + lane;

    float sg[8];
#pragma unroll
    for (int p = 0; p < 4; p++) {
        // load both groups' input fragments (8 x 16B global)
        shortx8 ub0[4], ub1[4];
#pragma unroll
        for (int kt = 0; kt < 4; kt++) {
            ub0[kt] = ua[((2 * p) * 4 + kt) * 64];
            ub1[kt] = ua[((2 * p + 1) * 4 + kt) * 64];
        }

        floatx4 acc0[4] = {}, acc1[4] = {};
#pragma unroll
        for (int kt = 0; kt < 4; kt++)
#pragma unroll
            for (int nt = 0; nt < 4; nt++) {
                shortx8 afr = wlds[(nt * 4 + kt) * 64 + lane];   // ds_read_b128
                acc0[nt] = __builtin_amdgcn_mfma_f32_16x16x32_bf16(afr, ub0[kt], acc0[nt], 0, 0, 0);
                acc1[nt] = __builtin_amdgcn_mfma_f32_16x16x32_bf16(afr, ub1[kt], acc1[nt], 0, 0, 0);
            }

        // epilogues (rcp-4): s += -2*w2/(exp2(y)+1), sum_h W2 lives in b2eff
#pragma unroll
        for (int e = 0; e < 2; e++) {
            const floatx4* ac = e ? acc1 : acc0;
            float s = 0.0f;
#pragma unroll
            for (int nt = 0; nt < 4; nt++) {
                float d0 = EXP2F(ac[nt][0]) + 1.0f;
                float d1 = EXP2F(ac[nt][1]) + 1.0f;
                float d2 = EXP2F(ac[nt][2]) + 1.0f;
                float d3 = EXP2F(ac[nt][3]) + 1.0f;
                float p01 = d0 * d1, p23 = d2 * d3;
                float ip = RCPF(p01 * p23);           // one rcp per 4 tanh
                float r01 = ip * p23;                 // = 1/(d0*d1)
                float r23 = ip * p01;                 // = 1/(d2*d3)
                s = fmaf(w2v[nt].x, r01 * d1, s);     // w2*(1/d0)
                s = fmaf(w2v[nt].y, r01 * d0, s);
                s = fmaf(w2v[nt].z, r23 * d3, s);
                s = fmaf(w2v[nt].w, r23 * d2, s);
            }
            sg[2 * p + e] = s;
        }
    }

    // deferred cross-quad reductions + stores (proven R7-R9)
#pragma unroll
    for (int g = 0; g < 8; g++) sg[g] += __shfl_xor(sg[g], 16, 64);
#pragma unroll
    for (int g = 0; g < 8; g++) sg[g] += __shfl_xor(sg[g], 32, 64);
    if (lane < 16) {
        float* outp = out + ((size_t)G0 * 16 + lane) * LATENT + lat;
#pragma unroll
        for (int g = 0; g < 8; g++)
            outp[g * 16 * LATENT] = sg[g] + b2v;
    }
}

// --- fp32 fallback (no workspace needed) ---
__global__ __launch_bounds__(256) void fallback_kernel(const float* __restrict__ u, const float* __restrict__ W1,
                                                       const float* __restrict__ b1, const float* __restrict__ W2,
                                                       const float* __restrict__ b2, float* __restrict__ out) {
    int idx = blockIdx.x * 256 + threadIdx.x;
    if (idx >= BATCH * LATENT) return;
    int b = idx >> 7;
    int lat = idx & 127;
    const float* ub = u + b * INDIM;
    float s = 0.0f;
    for (int h = 0; h < HIDDEN; h++) {
        const float* wp = W1 + (lat * HIDDEN + h) * INDIM;
        float dd = b1[lat * HIDDEN + h];
        for (int k = 0; k < INDIM; k++) dd += ub[k] * wp[k];
        s += tanhf(dd) * W2[lat * HIDDEN + h];
    }
    out[idx] = s + b2[lat];
}

extern "C" void kernel_launch(void* const* d_in, const int* in_sizes, int n_in,
                              void* d_out, int out_size, void* d_ws, size_t ws_size,
                              hipStream_t stream) {
    const float* u  = (const float*)d_in[0];
    const float* W1 = (const float*)d_in[1];
    const float* b1 = (const float*)d_in[2];
    const float* W2 = (const float*)d_in[3];
    const float* b2 = (const float*)d_in[4];
    float* out = (float*)d_out;

    const size_t UF_BYTES = (size_t)BATCH * KPAD * 2;           // 4 MiB
    const size_t WF_BYTES = (size_t)LATENT * HIDDEN * KPAD * 2; // 2 MiB
    const size_t B2_BYTES = LATENT * sizeof(float);

    if (ws_size < UF_BYTES + WF_BYTES + B2_BYTES) {
        fallback_kernel<<<(BATCH * LATENT + 255) / 256, 256, 0, stream>>>(u, W1, b1, W2, b2, out);
        return;
    }

    shortx8* uf = (shortx8*)d_ws;
    shortx8* wf = (shortx8*)((char*)d_ws + UF_BYTES);
    float* b2eff = (float*)((char*)d_ws + UF_BYTES + WF_BYTES);

    prep_all<<<N_U_BLK + N_W_BLK + 1, 256, 0, stream>>>(u, W1, b1, W2, b2, uf, wf, b2eff);
    branch_mlp<<<4096, 256, 0, stream>>>(uf, wf, W2, b2eff, out);
}

// Round 11
// 115.026 us; speedup vs baseline: 1.0117x; 1.0117x over previous
//
#include <hip/hip_runtime.h>

#define BATCH 16384
#define LATENT 128
#define HIDDEN 64
#define INDIM 100
#define KPAD 128
#define TANH_SCALE 2.885390081777927f   // 2*log2(e): exp(2x) = exp2(SCALE*x)

typedef short shortx8 __attribute__((ext_vector_type(8)));
typedef float floatx4 __attribute__((ext_vector_type(4)));

__device__ __forceinline__ unsigned bfbits(float f) {
    union { float f; unsigned u; } v; v.f = f;
    return (v.u + 0x7FFF + ((v.u >> 16) & 1)) >> 16;   // RNE, inputs finite
}

#if __has_builtin(__builtin_amdgcn_exp2f)
#define EXP2F(x) __builtin_amdgcn_exp2f(x)
#else
#define EXP2F(x) __exp2f(x)
#endif
#if __has_builtin(__builtin_amdgcn_rcpf)
#define RCPF(x) __builtin_amdgcn_rcpf(x)
#else
#define RCPF(x) (1.0f / (x))
#endif

#define N_U_BLK (BATCH / 16)                 // 1024 16-row tiles of u
#define N_W_BLK (LATENT * HIDDEN / 16)       // 512  16-row tiles of W1

// ---------------------------------------------------------------------------
// prep (R7, proven): 16-row LDS-transpose tiles, one per 256-thr block.
// ---------------------------------------------------------------------------
__global__ __launch_bounds__(256) void prep_all(const float* __restrict__ u,
                                                const float* __restrict__ W1,
                                                const float* __restrict__ b1,
                                                const float* __restrict__ W2,
                                                const float* __restrict__ b2,
                                                shortx8* __restrict__ uf,
                                                shortx8* __restrict__ wf,
                                                float* __restrict__ b2eff) {
    int bx = blockIdx.x;
    int tid = threadIdx.x;

    if (bx >= N_U_BLK + N_W_BLK) {           // b2eff block
        if (tid < LATENT) {
            float s = b2[tid];
            const float* wp = W2 + tid * HIDDEN;
#pragma unroll 8
            for (int h = 0; h < HIDDEN; h++) s += wp[h];
            b2eff[tid] = s;
        }
        return;
    }

    bool isW = (bx >= N_U_BLK);
    int tileIdx = isW ? (bx - N_U_BLK) : bx;
    int r0 = tileIdx * 16;
    const float* src = isW ? W1 : u;
    float scale = isW ? TANH_SCALE : 1.0f;

    __shared__ short lds[16 * 136];

#pragma unroll
    for (int it = 0; it < 4; it++) {
        int p = it * 256 + tid;
        int rl = p >> 6;
        int kp = (p & 63) * 2;
        float f0 = 0.0f, f1 = 0.0f;
        if (kp < INDIM) {
            const float2 t = *(const float2*)(src + (r0 + rl) * INDIM + kp);
            f0 = t.x * scale; f1 = t.y * scale;
        } else if (kp == INDIM) {
            f0 = isW ? b1[r0 + rl] * TANH_SCALE : 1.0f;
        }
        *(unsigned*)(&lds[rl * 136 + kp]) = bfbits(f0) | (bfbits(f1) << 16);
    }
    __syncthreads();

    {
        int lane = tid & 63;
        int kt = tid >> 6;
        int rl = lane & 15;
        int kb = kt * 32 + ((lane >> 4) << 3);
        shortx8 v = *(const shortx8*)(&lds[rl * 136 + kb]);
        shortx8* dst = isW ? wf : uf;
        dst[((size_t)tileIdx * 4 + kt) * 64 + lane] = v;
    }
}

// ---------------------------------------------------------------------------
// R11 main kernel: MINIMAL REGISTER FOOTPRINT for residency.
// R6-R10 all sat at ~50us with OccupancyPercent ~25% (2 waves/SIMD): the
// unified VGPR+AGPR allocation (arch 80 + accs) crossed into the low-
// residency bin, so the matrix and VALU pipes never overlapped cross-wave.
// This round strips per-wave state to ~65 regs:
//   - weights AND -2*W2 in LDS (shared by 4 waves)      [-80 regs]
//   - single ub buffer, single acc set, no deferred sg   [-40 regs]
//   - kt=0 MFMA takes a persistent ZERO as C operand -> no 32x
//     v_accvgpr_write per group (~15% of VALU work)
//   - __launch_bounds__(256,6): allocator capped ~85 regs -> 6 waves/SIMD
// Epilogue (proven): exp2 direct (scale in W1), rcp-4, sum_h W2 in b2eff.
// ---------------------------------------------------------------------------
__global__ __launch_bounds__(256, 6) void branch_mlp(const shortx8* __restrict__ uf,
                                                     const shortx8* __restrict__ wf,
                                                     const float* __restrict__ W2,
                                                     const float* __restrict__ b2eff,
                                                     float* __restrict__ out) {
    __shared__ shortx8 wlds[16 * 64];        // 16 KB: this latent's W1 fragments
    __shared__ float w2lds[HIDDEN];          // -2*W2 for this latent
    int tid = threadIdx.x;
    int lane = tid & 63;
    int w = tid >> 6;
    int bx = blockIdx.x;
    int lat = bx >> 5;
    int G0 = (bx & 31) * 32 + w * 8;
    int q = lane >> 4;

    {
        const shortx8* wfl = wf + (size_t)lat * 16 * 64;
#pragma unroll
        for (int j = 0; j < 4; j++) {
            int i = j * 256 + tid;
            wlds[i] = wfl[i];
        }
        if (tid < HIDDEN) w2lds[tid] = -2.0f * W2[lat * HIDDEN + tid];
    }
    float b2v = b2eff[lat];
    __syncthreads();

    const shortx8* ua = uf + (size_t)G0 * 4 * 64 + lane;
    const floatx4 ZERO = {0.0f, 0.0f, 0.0f, 0.0f};

#pragma unroll
    for (int g = 0; g < 8; g++) {
        shortx8 ub[4];
#pragma unroll
        for (int kt = 0; kt < 4; kt++)
            ub[kt] = ua[(g * 4 + kt) * 64];

        floatx4 acc[4];
#pragma unroll
        for (int kt = 0; kt < 4; kt++)
#pragma unroll
            for (int nt = 0; nt < 4; nt++) {
                shortx8 afr = wlds[(nt * 4 + kt) * 64 + lane];   // ds_read_b128
                acc[nt] = __builtin_amdgcn_mfma_f32_16x16x32_bf16(
                    afr, ub[kt], (kt == 0) ? ZERO : acc[nt], 0, 0, 0);
            }

        // epilogue: s += -2*w2/(exp2(y)+1) per this lane's 16 h; rcp-4
        float s = 0.0f;
#pragma unroll
        for (int nt = 0; nt < 4; nt++) {
            const float4 w2 = *(const float4*)(&w2lds[nt * 16 + q * 4]);
            float d0 = EXP2F(acc[nt][0]) + 1.0f;
            float d1 = EXP2F(acc[nt][1]) + 1.0f;
            float d2 = EXP2F(acc[nt][2]) + 1.0f;
            float d3 = EXP2F(acc[nt][3]) + 1.0f;
            float p01 = d0 * d1, p23 = d2 * d3;
            float ip = RCPF(p01 * p23);           // one rcp per 4 tanh
            float r01 = ip * p23;                 // 1/(d0*d1)
            float r23 = ip * p01;                 // 1/(d2*d3)
            s = fmaf(w2.x, r01 * d1, s);
            s = fmaf(w2.y, r01 * d0, s);
            s = fmaf(w2.z, r23 * d3, s);
            s = fmaf(w2.w, r23 * d2, s);
        }
        s += __shfl_xor(s, 16, 64);
        s += __shfl_xor(s, 32, 64);
        if (lane < 16)
            out[((size_t)(G0 + g) * 16 + lane) * LATENT + lat] = s + b2v;
    }
}

// --- fp32 fallback (no workspace needed) ---
__global__ __launch_bounds__(256) void fallback_kernel(const float* __restrict__ u, const float* __restrict__ W1,
                                                       const float* __restrict__ b1, const float* __restrict__ W2,
                                                       const float* __restrict__ b2, float* __restrict__ out) {
    int idx = blockIdx.x * 256 + threadIdx.x;
    if (idx >= BATCH * LATENT) return;
    int b = idx >> 7;
    int lat = idx & 127;
    const float* ub = u + b * INDIM;
    float s = 0.0f;
    for (int h = 0; h < HIDDEN; h++) {
        const float* wp = W1 + (lat * HIDDEN + h) * INDIM;
        float dd = b1[lat * HIDDEN + h];
        for (int k = 0; k < INDIM; k++) dd += ub[k] * wp[k];
        s += tanhf(dd) * W2[lat * HIDDEN + h];
    }
    out[idx] = s + b2[lat];
}

extern "C" void kernel_launch(void* const* d_in, const int* in_sizes, int n_in,
                              void* d_out, int out_size, void* d_ws, size_t ws_size,
                              hipStream_t stream) {
    const float* u  = (const float*)d_in[0];
    const float* W1 = (const float*)d_in[1];
    const float* b1 = (const float*)d_in[2];
    const float* W2 = (const float*)d_in[3];
    const float* b2 = (const float*)d_in[4];
    float* out = (float*)d_out;

    const size_t UF_BYTES = (size_t)BATCH * KPAD * 2;           // 4 MiB
    const size_t WF_BYTES = (size_t)LATENT * HIDDEN * KPAD * 2; // 2 MiB
    const size_t B2_BYTES = LATENT * sizeof(float);

    if (ws_size < UF_BYTES + WF_BYTES + B2_BYTES) {
        fallback_kernel<<<(BATCH * LATENT + 255) / 256, 256, 0, stream>>>(u, W1, b1, W2, b2, out);
        return;
    }

    shortx8* uf = (shortx8*)d_ws;
    shortx8* wf = (shortx8*)((char*)d_ws + UF_BYTES);
    float* b2eff = (float*)((char*)d_ws + UF_BYTES + WF_BYTES);

    prep_all<<<N_U_BLK + N_W_BLK + 1, 256, 0, stream>>>(u, W1, b1, W2, b2, uf, wf, b2eff);
    branch_mlp<<<4096, 256, 0, stream>>>(uf, wf, W2, b2eff, out);
}